// Round 8
// baseline (45.137 us; speedup 1.0000x reference)
//
#include <hip/hip_runtime.h>

// out[d][c][h][w] = (h < d) ? left[c][h][w] - right[c][h + 128 - d][w] : 0
// N=1, C=16, H=128, W=256, D=128. Output (1,128,16,128,256) fp32 = 256 MiB.
//
// Structure (R7): per-wave 8x8 row-pair tiles (64 output rows from 16 loads),
// diagonal store order (fixed a-b -> same d-slice, consecutive h), zero
// region as slice pairs (d,127-d) split 65/64 across two waves.
//
// NEW (R8): XCD-aware channel partitioning. A wave only reads input channel
// c; pin channels {2x, 2x+1} to XCD x via the round-robin blockIdx%8->XCD
// dispatch. Each XCD's L2 then holds only 0.5 MiB of inputs (vs all 4 MiB),
// cutting compulsory HBM input fetch ~32 MiB -> ~4 MiB and making all data
// loads local-L2 hits. Per channel: 120 full + 16 diag + 128 zero = 264
// waves = 66 blocks; 2 channels/XCD = 132 blocks/XCD; 8 XCDs = 1056 blocks.
// NOTE: nt-stores regressed twice (R2, R4) -> plain stores only.

typedef float f32x4 __attribute__((ext_vector_type(4)));

__global__ __launch_bounds__(256) void CostDifference_kernel(
    const f32x4* __restrict__ left,
    const f32x4* __restrict__ right,
    f32x4* __restrict__ out)
{
    const int lane = threadIdx.x & 63;

    // ---- XCD-aware work decode (all wave-uniform) ----
    const int x  = blockIdx.x & 7;               // XCD (round-robin heuristic)
    const int k  = blockIdx.x >> 3;              // 0..131 within XCD
    const int wk = (k << 2) | (threadIdx.x >> 6);// 0..527 wave within XCD
    const int second = (wk >= 264) ? 1 : 0;
    const int c     = (x << 1) | second;         // this wave's channel
    const int local = wk - second * 264;         // 0..263 within channel

    if (local < 120) {
        // ---- full 8x8 row-pair tile, i < j ----
        int p = local;                           // 0..119
        int i = 0;
        while (p >= 15 - i) { p -= 15 - i; ++i; }   // wave-uniform decode
        const int j = i + 1 + p;

        const int i8 = i << 3, j8 = j << 3;
        f32x4 L[8], R[8];
#pragma unroll
        for (int a = 0; a < 8; ++a) L[a] = left [(c * 128 + i8 + a) * 64 + lane];
#pragma unroll
        for (int b = 0; b < 8; ++b) R[b] = right[(c * 128 + j8 + b) * 64 + lane];

        // d = 128 + i8 - j8 + (a-b); row = d*2048 + c*128 + i8 + a
        // diagonal order: ab = a-b fixed -> same slice, consecutive h
        const int base = (128 + i8 - j8) * 2048 + c * 128 + i8;
#pragma unroll
        for (int ab = -7; ab <= 7; ++ab) {
            const int lo = ab > 0 ? ab : 0;
            const int hi = ab < 0 ? 7 + ab : 7;
#pragma unroll
            for (int a = lo; a <= hi; ++a) {
                const int b = a - ab;
                const int row = base + a + ab * 2048;
                f32x4 o;
                o.x = L[a].x - R[b].x;
                o.y = L[a].y - R[b].y;
                o.z = L[a].z - R[b].z;
                o.w = L[a].w - R[b].w;
                out[row * 64 + lane] = o;
            }
        }
    } else if (local < 136) {
        // ---- diag tile i == j: pairs a < b (28 rows), diagonal order ----
        const int i8 = (local - 120) << 3;
        f32x4 L[8], R[8];
#pragma unroll
        for (int a = 0; a < 8; ++a) L[a] = left [(c * 128 + i8 + a) * 64 + lane];
#pragma unroll
        for (int b = 0; b < 8; ++b) R[b] = right[(c * 128 + i8 + b) * 64 + lane];

        const int base = 128 * 2048 + c * 128 + i8;   // i8 - j8 == 0
#pragma unroll
        for (int ab = -7; ab <= -1; ++ab) {
#pragma unroll
            for (int a = 0; a <= 7 + ab; ++a) {
                const int b = a - ab;
                const int row = base + a + ab * 2048;
                f32x4 o;
                o.x = L[a].x - R[b].x;
                o.y = L[a].y - R[b].y;
                o.z = L[a].z - R[b].z;
                o.w = L[a].w - R[b].w;
                out[row * 64 + lane] = o;
            }
        }
    } else {
        // ---- zero waves: slice pair (d, 127-d), 129 rows split 65/64 ----
        const int t    = local - 136;            // 0..127
        const int d    = t >> 1;                 // 0..63
        const int half = t & 1;
        const int d2   = 127 - d;
        const int n1   = 128 - d;                // zero rows in slice d
        const int start = half ? 65 : 0;
        const int end   = half ? 129 : 65;
        const f32x4 zero = {0.f, 0.f, 0.f, 0.f};

        // slice d: rows d+kk for kk in [start, min(end, n1))
        const int e1 = min(end, n1);
        int rb = (d * 2048 + c * 128 + d + start) * 64 + lane;
        for (int kk = start; kk < e1; ++kk, rb += 64) out[rb] = zero;

        // slice d2: rows d2+(kk-n1) for kk in [max(start, n1), end)
        const int s2 = max(start, n1);
        rb = (d2 * 2048 + c * 128 + d2 + (s2 - n1)) * 64 + lane;
        for (int kk = s2; kk < end; ++kk, rb += 64) out[rb] = zero;
    }
}

extern "C" void kernel_launch(void* const* d_in, const int* in_sizes, int n_in,
                              void* d_out, int out_size, void* d_ws, size_t ws_size,
                              hipStream_t stream) {
    const f32x4* left  = (const f32x4*)d_in[0];
    const f32x4* right = (const f32x4*)d_in[1];
    f32x4* out = (f32x4*)d_out;

    CostDifference_kernel<<<1056, 256, 0, stream>>>(left, right, out);
}

// Round 9
// 42.210 us; speedup vs baseline: 1.0693x; 1.0693x over previous
//
#include <hip/hip_runtime.h>

// out[d][c][h][w] = (h < d) ? left[c][h][w] - right[c][h + 128 - d][w] : 0
// N=1, C=16, H=128, W=256, D=128. Output (1,128,16,128,256) fp32 = 256 MiB.
//
// R7 structure + LDS block-sharing: the 4 waves of a block compute the 4
// 8x8 quadrants of a 16x16-row super-tile (row groups I<J of 16). The block
// stages 32 input rows (32 KiB) in LDS once; each wave register-loads its
// 8 L + 8 R rows from LDS -> global reads drop 34 MiB -> ~20 MiB.
// Stores unchanged: diagonal order (fixed a-b -> same d-slice, consecutive
// h). Zero region: slice pairs (d,127-d), 129 rows split 65/64 per 2 waves.
// NOTE: nt-stores regressed (R2,R4); L2 locality games futile (R8): the
// write stream evicts L2 regardless.
//
// Per channel c (16 total): 28 LDS blocks + 8 reg blocks = 66 blocks.
//   reg-block waves wk = (r-28)*4+w in [0,152):
//     [0,8)    off-diag in-group tiles (i8=16g, j8=16g+8), 64 rows
//     [8,24)   diag tiles i8=8*(wk-8), 28 rows
//     [24,152) zero waves, ~64.5 rows
// Grid: 16 * 66 = 1056 blocks.

typedef float f32x4 __attribute__((ext_vector_type(4)));

__device__ __forceinline__ void store_tile(f32x4* __restrict__ out,
                                           const f32x4 (&L)[8],
                                           const f32x4 (&R)[8],
                                           int base) {
    // diagonal order: ab = a-b fixed -> same d-slice, consecutive h
#pragma unroll
    for (int ab = -7; ab <= 7; ++ab) {
        const int lo = ab > 0 ? ab : 0;
        const int hi = ab < 0 ? 7 + ab : 7;
#pragma unroll
        for (int a = lo; a <= hi; ++a) {
            const int b = a - ab;
            f32x4 o;
            o.x = L[a].x - R[b].x;
            o.y = L[a].y - R[b].y;
            o.z = L[a].z - R[b].z;
            o.w = L[a].w - R[b].w;
            out[(base + a + ab * 2048) * 64] = o;
        }
    }
}

__global__ __launch_bounds__(256) void CostDifference_kernel(
    const f32x4* __restrict__ left,
    const f32x4* __restrict__ right,
    f32x4* __restrict__ out)
{
    __shared__ f32x4 lds[32][64];                // 32 KiB
    const int lane = threadIdx.x & 63;
    const int w    = threadIdx.x >> 6;

    const int c = blockIdx.x / 66;               // block-uniform
    const int r = blockIdx.x - c * 66;

    if (r < 28) {
        // ---- LDS-shared super-tile: 16-row groups I < J ----
        int p = r, I = 0;
        while (p >= 7 - I) { p -= 7 - I; ++I; }
        const int J = I + 1 + p;

        // cooperative stage: 32 rows; wave w loads rows w, 4+w, ..., 28+w
        const int base_l = (c * 128 + (I << 4)) * 64 + lane;
        const int base_r = (c * 128 + (J << 4)) * 64 + lane;
#pragma unroll
        for (int k = 0; k < 8; ++k) {
            const int row = (k << 2) + w;        // wave-uniform per k
            lds[row][lane] = (row < 16) ? left [base_l + (row << 6)]
                                        : right[base_r + ((row - 16) << 6)];
        }
        __syncthreads();

        const int qa = (w >> 1) & 1, qb = w & 1;
        f32x4 L[8], R[8];
#pragma unroll
        for (int a = 0; a < 8; ++a) L[a] = lds[(qa << 3) + a][lane];
#pragma unroll
        for (int b = 0; b < 8; ++b) R[b] = lds[16 + (qb << 3) + b][lane];

        const int i8 = (I << 4) + (qa << 3);
        const int j8 = (J << 4) + (qb << 3);
        const int base = (128 + i8 - j8) * 2048 + c * 128 + i8;
        store_tile(out + lane, L, R, base);
    } else {
        const int wk = ((r - 28) << 2) | w;      // 0..151, wave-uniform
        if (wk < 8) {
            // ---- in-group off-diag tile: i8=16g, j8=16g+8 ----
            const int i8 = wk << 4, j8 = i8 + 8;
            f32x4 L[8], R[8];
#pragma unroll
            for (int a = 0; a < 8; ++a) L[a] = left [(c * 128 + i8 + a) * 64 + lane];
#pragma unroll
            for (int b = 0; b < 8; ++b) R[b] = right[(c * 128 + j8 + b) * 64 + lane];
            const int base = (128 + i8 - j8) * 2048 + c * 128 + i8;
            store_tile(out + lane, L, R, base);
        } else if (wk < 24) {
            // ---- diag tile i8 == j8: pairs a < b (28 rows) ----
            const int i8 = (wk - 8) << 3;
            f32x4 L[8], R[8];
#pragma unroll
            for (int a = 0; a < 8; ++a) L[a] = left [(c * 128 + i8 + a) * 64 + lane];
#pragma unroll
            for (int b = 0; b < 8; ++b) R[b] = right[(c * 128 + i8 + b) * 64 + lane];
            const int base = 128 * 2048 + c * 128 + i8;
#pragma unroll
            for (int ab = -7; ab <= -1; ++ab) {
#pragma unroll
                for (int a = 0; a <= 7 + ab; ++a) {
                    const int b = a - ab;
                    f32x4 o;
                    o.x = L[a].x - R[b].x;
                    o.y = L[a].y - R[b].y;
                    o.z = L[a].z - R[b].z;
                    o.w = L[a].w - R[b].w;
                    out[(base + a + ab * 2048) * 64 + lane] = o;
                }
            }
        } else {
            // ---- zero waves: slice pair (d, 127-d), 129 rows 65/64 ----
            const int t    = wk - 24;            // 0..127
            const int d    = t >> 1;
            const int half = t & 1;
            const int d2   = 127 - d;
            const int n1   = 128 - d;
            const int start = half ? 65 : 0;
            const int end   = half ? 129 : 65;
            const f32x4 zero = {0.f, 0.f, 0.f, 0.f};

            const int e1 = min(end, n1);
            int rb = (d * 2048 + c * 128 + d + start) * 64 + lane;
            for (int kk = start; kk < e1; ++kk, rb += 64) out[rb] = zero;

            const int s2 = max(start, n1);
            rb = (d2 * 2048 + c * 128 + d2 + (s2 - n1)) * 64 + lane;
            for (int kk = s2; kk < end; ++kk, rb += 64) out[rb] = zero;
        }
    }
}

extern "C" void kernel_launch(void* const* d_in, const int* in_sizes, int n_in,
                              void* d_out, int out_size, void* d_ws, size_t ws_size,
                              hipStream_t stream) {
    const f32x4* left  = (const f32x4*)d_in[0];
    const f32x4* right = (const f32x4*)d_in[1];
    f32x4* out = (f32x4*)d_out;

    CostDifference_kernel<<<1056, 256, 0, stream>>>(left, right, out);
}